// Round 8
// baseline (430.522 us; speedup 1.0000x reference)
//
#include <hip/hip_runtime.h>
#include <math.h>

// SOR defense: B=4, K=8192, 3D points. kNN k=2 (3 smallest incl. self).
// Outputs: masked_pc [4,8192,3] then mask [4,8192] (floats).
//
// Exact grid-accelerated kNN: bin points into a 48^3 grid over fixed bounds,
// expand Chebyshev shells per query until the 3rd-smallest distance is
// provably below the distance to any unvisited cell (conservative margin).
// Distance expression textually identical to the validated all-pairs rounds
// -> bit-identical top-3 multiset -> identical value/threshold/mask.

constexpr int B = 4;
constexpr int K = 8192;
constexpr int BK = B * K;
constexpr int G = 48;
constexpr int NC = G * G * G;   // 110592
constexpr int NCP1 = NC + 1;
constexpr float LOB = -5.5f;
constexpr float HIB = 5.5f;

#define BIG 3.0e38f

// Exact top-3 insert via med3 (pure selection, exact order statistics).
#define MINSERT(d, e0, e1, e2)                                  \
  do {                                                          \
    const float n0_ = fminf((e0), (d));                         \
    const float n1_ = __builtin_amdgcn_fmed3f((d), (e0), (e1)); \
    const float n2_ = __builtin_amdgcn_fmed3f((d), (e1), (e2)); \
    (e0) = n0_; (e1) = n1_; (e2) = n2_;                         \
  } while (0)

// Pack (x,y,z,||p||^2), compute cell id, histogram counts.
// Norm expression identical to reference xx -> bit-identical downstream.
__global__ __launch_bounds__(256) void pack_cell_kernel(
    const float* __restrict__ x, float4* __restrict__ pack,
    int* __restrict__ cellid, int* __restrict__ counts) {
  const int g = blockIdx.x * 256 + threadIdx.x;  // over B*K
  const int b = g / K;
  const float px = x[(size_t)g * 3 + 0];
  const float py = x[(size_t)g * 3 + 1];
  const float pz = x[(size_t)g * 3 + 2];
  pack[g] = make_float4(px, py, pz, (px * px + py * py) + pz * pz);

  const float SC = (float)G / (HIB - LOB);
  int cx = (int)((px - LOB) * SC); cx = min(max(cx, 0), G - 1);
  int cy = (int)((py - LOB) * SC); cy = min(max(cy, 0), G - 1);
  int cz = (int)((pz - LOB) * SC); cz = min(max(cz, 0), G - 1);
  const int c = (cz * G + cy) * G + cx;
  cellid[g] = c;
  atomicAdd(&counts[b * NC + c], 1);
}

// Per-batch exclusive prefix sum over NC cells; writes offs (NCP1) + cursor.
__global__ __launch_bounds__(1024) void scan_kernel(
    const int* __restrict__ counts, int* __restrict__ offs,
    int* __restrict__ cursor) {
  const int b = blockIdx.x;
  const int t = threadIdx.x;
  constexpr int CPB = NC / 1024;  // 108
  const int base = b * NC + t * CPB;

  int sum = 0;
  for (int i = 0; i < CPB; ++i) sum += counts[base + i];

  __shared__ int ss[1024];
  ss[t] = sum;
  __syncthreads();
  for (int off = 1; off < 1024; off <<= 1) {  // Hillis-Steele inclusive
    const int v = (t >= off) ? ss[t - off] : 0;
    __syncthreads();
    ss[t] += v;
    __syncthreads();
  }

  int run = ss[t] - sum;  // exclusive start (batch-local)
  const int obase = b * NCP1;
  for (int i = 0; i < CPB; ++i) {
    const int cell = t * CPB + i;
    offs[obase + cell] = run;
    cursor[obase + cell] = run;
    run += counts[base + i];
  }
  if (t == 1023) offs[obase + NC] = run;  // == K
}

// Scatter points into cell-sorted order (order within a cell is
// nondeterministic, but top-3 is a multiset -> outputs unaffected).
__global__ __launch_bounds__(256) void scatter_kernel(
    const float4* __restrict__ pack, const int* __restrict__ cellid,
    int* __restrict__ cursor, float4* __restrict__ spts,
    int* __restrict__ sidx, int* __restrict__ cells_s) {
  const int g = blockIdx.x * 256 + threadIdx.x;
  const int b = g / K;
  const int c = cellid[g];
  const int pos = atomicAdd(&cursor[b * NCP1 + c], 1);
  spts[b * K + pos] = pack[g];
  sidx[b * K + pos] = g - b * K;  // original k
  cells_s[b * K + pos] = c;
}

// Exact kNN via expanding Chebyshev shells + conservative face-distance prune.
__global__ __launch_bounds__(64) void search_kernel(
    const float4* __restrict__ spts, const int* __restrict__ sidx,
    const int* __restrict__ cells_s, const int* __restrict__ offs,
    float* __restrict__ value) {
  const int gq = blockIdx.x * 64 + threadIdx.x;  // over B*K (scattered order)
  const int b = gq / K;
  const int sbase = b * K;
  const int obase = b * NCP1;

  const float4 q = spts[gq];
  const float qx = q.x, qy = q.y, qz = q.z, qn = q.w;
  const int c = cells_s[gq];
  const int cx = c % G, cy = (c / G) % G, cz = c / (G * G);
  const float w = (HIB - LOB) / (float)G;

  float e0 = BIG, e1 = BIG, e2 = BIG;

#define PAIR(I)                                                    \
  do {                                                             \
    const float4 sp = spts[sbase + (I)];                           \
    const float dot_ = (qx * sp.x + qy * sp.y) + qz * sp.z;        \
    const float d_ = (qn - 2.0f * dot_) + sp.w;                    \
    MINSERT(d_, e0, e1, e2);                                       \
  } while (0)

  for (int s = 0; s < G; ++s) {
    const int zlo = max(cz - s, 0), zhi = min(cz + s, G - 1);
    for (int z = zlo; z <= zhi; ++z) {
      const bool zface = (z == cz - s) || (z == cz + s);
      const int ylo = max(cy - s, 0), yhi = min(cy + s, G - 1);
      for (int y = ylo; y <= yhi; ++y) {
        const int rowb = obase + (z * G + y) * G;
        if (zface || y == cy - s || y == cy + s) {
          // full x-range: cells are x-contiguous -> one [st,en) span
          const int xlo = max(cx - s, 0), xhi = min(cx + s, G - 1);
          const int st = offs[rowb + xlo];
          const int en = offs[rowb + xhi + 1];
          int i = st;
          for (; i + 2 <= en; i += 2) { PAIR(i); PAIR(i + 1); }
          if (i < en) PAIR(i);
        } else {
          int xx = cx - s;
          if (xx >= 0) {
            const int st = offs[rowb + xx], en = offs[rowb + xx + 1];
            for (int i = st; i < en; ++i) PAIR(i);
          }
          xx = cx + s;
          if (xx < G) {
            const int st = offs[rowb + xx], en = offs[rowb + xx + 1];
            for (int i = st; i < en; ++i) PAIR(i);
          }
        }
      }
    }
    // Prune: min distance from q to any unvisited cell (face of visited box;
    // grid edge -> +inf, which also makes clamped-outlier handling exact).
    const float rxlo = (cx - s >= 1)     ? (qx - (LOB + (float)(cx - s) * w))     : BIG;
    const float rxhi = (cx + s + 1 <= G - 1) ? ((LOB + (float)(cx + s + 1) * w) - qx) : BIG;
    const float rylo = (cy - s >= 1)     ? (qy - (LOB + (float)(cy - s) * w))     : BIG;
    const float ryhi = (cy + s + 1 <= G - 1) ? ((LOB + (float)(cy + s + 1) * w) - qy) : BIG;
    const float rzlo = (cz - s >= 1)     ? (qz - (LOB + (float)(cz - s) * w))     : BIG;
    const float rzhi = (cz + s + 1 <= G - 1) ? ((LOB + (float)(cz + s + 1) * w) - qz) : BIG;
    const float rmin = fminf(fminf(fminf(rxlo, rxhi), fminf(rylo, ryhi)),
                             fminf(rzlo, rzhi));
    const float rs = fmaxf(rmin - 1e-5f, 0.0f);  // margin > all fl rounding
    if (e2 < 1e37f && e2 <= rs * rs) break;
  }
#undef PAIR

  // drop self (e0), mean of 2 kNN; same op order as reference mean.
  value[sbase + sidx[gq]] = 0.5f * (e1 + e2);
}

// Per-256-chunk double sums of value (fixed order -> deterministic).
__global__ __launch_bounds__(256) void bsum_kernel(
    const float* __restrict__ value, double* __restrict__ bsum) {
  const int blk = blockIdx.x;  // b*32 + sub  (K = 32*256)
  const int tid = threadIdx.x;
  const float v = value[blk * 256 + tid];

  double s = (double)v, s2 = (double)v * (double)v;
  for (int off = 32; off > 0; off >>= 1) {
    s  += __shfl_down(s, off, 64);
    s2 += __shfl_down(s2, off, 64);
  }
  __shared__ double rs[4], rs2[4];
  const int wave = tid >> 6;
  if ((tid & 63) == 0) { rs[wave] = s; rs2[wave] = s2; }
  __syncthreads();
  if (tid == 0) {
    double S = 0.0, S2 = 0.0;
    for (int wv = 0; wv < 4; ++wv) { S += rs[wv]; S2 += rs2[wv]; }
    bsum[blk * 2 + 0] = S;
    bsum[blk * 2 + 1] = S2;
  }
}

// Threshold (recomputed per block, fixed order) + mask apply.
__global__ __launch_bounds__(256) void sor_mask_kernel(
    const float* __restrict__ x, const float* __restrict__ value,
    const double* __restrict__ bsum, float* __restrict__ out) {
  const int g = blockIdx.x * 256 + threadIdx.x;  // b*K + k
  const int b = g / K;

  __shared__ float sthr;
  if (threadIdx.x == 0) {
    double S = 0.0, S2 = 0.0;
    for (int wv = 0; wv < 32; ++wv) {
      S  += bsum[(b * 32 + wv) * 2 + 0];
      S2 += bsum[(b * 32 + wv) * 2 + 1];
    }
    const double mean = S / (double)K;
    const double var  = (S2 - S * S / (double)K) / (double)(K - 1);
    sthr = (float)(mean + 1.1 * sqrt(var));
  }
  __syncthreads();

  const float m = (value[g] <= sthr) ? 1.0f : 0.0f;
  out[(size_t)BK * 3 + g] = m;
  const size_t base = (size_t)g * 3;
  out[base + 0] = x[base + 0] * m;
  out[base + 1] = x[base + 1] * m;
  out[base + 2] = x[base + 2] * m;
}

extern "C" void kernel_launch(void* const* d_in, const int* in_sizes, int n_in,
                              void* d_out, int out_size, void* d_ws, size_t ws_size,
                              hipStream_t stream) {
  const float* x = (const float*)d_in[0];
  float* out = (float*)d_out;
  char* ws = (char*)d_ws;

  size_t off = 0;
  float4* pack = (float4*)(ws + off); off += (size_t)BK * sizeof(float4);
  float4* spts = (float4*)(ws + off); off += (size_t)BK * sizeof(float4);
  int* cellid  = (int*)(ws + off);    off += (size_t)BK * sizeof(int);
  int* sidx    = (int*)(ws + off);    off += (size_t)BK * sizeof(int);
  int* cells_s = (int*)(ws + off);    off += (size_t)BK * sizeof(int);
  int* counts  = (int*)(ws + off);    off += (size_t)B * NC * sizeof(int);
  int* offs    = (int*)(ws + off);    off += (size_t)B * NCP1 * sizeof(int);
  int* cursor  = (int*)(ws + off);    off += (size_t)B * NCP1 * sizeof(int);
  float* value = (float*)(ws + off);  off += (size_t)BK * sizeof(float);
  off = (off + 15) & ~(size_t)15;
  double* bsum = (double*)(ws + off);

  hipMemsetAsync(counts, 0, (size_t)B * NC * sizeof(int), stream);
  pack_cell_kernel<<<BK / 256, 256, 0, stream>>>(x, pack, cellid, counts);
  scan_kernel<<<B, 1024, 0, stream>>>(counts, offs, cursor);
  scatter_kernel<<<BK / 256, 256, 0, stream>>>(pack, cellid, cursor,
                                               spts, sidx, cells_s);
  search_kernel<<<BK / 64, 64, 0, stream>>>(spts, sidx, cells_s, offs, value);
  bsum_kernel<<<BK / 256, 256, 0, stream>>>(value, bsum);
  sor_mask_kernel<<<BK / 256, 256, 0, stream>>>(x, value, bsum, out);
}

// Round 9
// 339.944 us; speedup vs baseline: 1.2665x; 1.2665x over previous
//
#include <hip/hip_runtime.h>
#include <math.h>

// SOR defense: B=4, K=8192, 3D points. kNN k=2 (3 smallest incl. self).
// Outputs: masked_pc [4,8192,3] then mask [4,8192] (floats).
//
// Exact grid kNN, wave-per-query: shell walk is wave-uniform (scalar), the
// 64 lanes sweep candidate spans in parallel (coalesced float4). Per-lane
// top-3 with exact shfl_down tree merges. Distance expression textually
// identical to the validated all-pairs rounds -> bit-identical outputs.

constexpr int B = 4;
constexpr int K = 8192;
constexpr int BK = B * K;
constexpr int G = 32;
constexpr int NC = G * G * G;    // 32768
constexpr int OST = NC + 4;      // padded per-batch stride (int4-aligned)
constexpr float LOB = -3.0f;
constexpr float HIB = 3.0f;
constexpr float CW = (HIB - LOB) / (float)G;  // 0.1875, dyadic-exact

#define BIG 3.0e38f

// Exact top-3 insert via med3 (pure selection, exact order statistics).
#define MINSERT(d, e0, e1, e2)                                  \
  do {                                                          \
    const float n0_ = fminf((e0), (d));                         \
    const float n1_ = __builtin_amdgcn_fmed3f((d), (e0), (e1)); \
    const float n2_ = __builtin_amdgcn_fmed3f((d), (e1), (e2)); \
    (e0) = n0_; (e1) = n1_; (e2) = n2_;                         \
  } while (0)

// Pack (x,y,z,||p||^2), cell id, histogram. Norm expression identical to
// reference xx -> bit-identical downstream.
__global__ __launch_bounds__(256) void pack_cell_kernel(
    const float* __restrict__ x, float4* __restrict__ pack,
    int* __restrict__ cellid, int* __restrict__ counts) {
  const int g = blockIdx.x * 256 + threadIdx.x;  // over B*K
  const int b = g / K;
  const float px = x[(size_t)g * 3 + 0];
  const float py = x[(size_t)g * 3 + 1];
  const float pz = x[(size_t)g * 3 + 2];
  pack[g] = make_float4(px, py, pz, (px * px + py * py) + pz * pz);

  const float SC = (float)G / (HIB - LOB);
  int cx = (int)((px - LOB) * SC); cx = min(max(cx, 0), G - 1);
  int cy = (int)((py - LOB) * SC); cy = min(max(cy, 0), G - 1);
  int cz = (int)((pz - LOB) * SC); cz = min(max(cz, 0), G - 1);
  const int c = (cz * G + cy) * G + cx;
  cellid[g] = c;
  atomicAdd(&counts[b * NC + c], 1);
}

// Per-batch exclusive scan over NC cells (1024 threads, 32 cells each,
// int4-vectorized). offs has stride OST per batch; cursor = copy for scatter.
__global__ __launch_bounds__(1024) void scan_kernel(
    const int* __restrict__ counts, int* __restrict__ offs,
    int* __restrict__ cursor) {
  const int b = blockIdx.x;
  const int t = threadIdx.x;
  const int base = b * NC + t * 32;

  int4 c[8];
  const int4* cp = (const int4*)(counts + base);
  int sum = 0;
#pragma unroll
  for (int i = 0; i < 8; ++i) {
    c[i] = cp[i];
    sum += c[i].x + c[i].y + c[i].z + c[i].w;
  }

  __shared__ int ss[1024];
  ss[t] = sum;
  __syncthreads();
  for (int off = 1; off < 1024; off <<= 1) {  // Hillis-Steele inclusive
    const int v = (t >= off) ? ss[t - off] : 0;
    __syncthreads();
    ss[t] += v;
    __syncthreads();
  }

  int run = ss[t] - sum;  // exclusive start
  const int obase = b * OST;
  int4* op = (int4*)(offs + obase + t * 32);
  int4* up = (int4*)(cursor + obase + t * 32);
#pragma unroll
  for (int i = 0; i < 8; ++i) {
    int4 o;
    o.x = run; run += c[i].x;
    o.y = run; run += c[i].y;
    o.z = run; run += c[i].z;
    o.w = run; run += c[i].w;
    op[i] = o;
    up[i] = o;
  }
  if (t == 1023) offs[obase + NC] = run;  // == K
}

// Scatter into cell-sorted order (in-cell order nondeterministic; top-3 is a
// multiset -> outputs unaffected).
__global__ __launch_bounds__(256) void scatter_kernel(
    const float4* __restrict__ pack, const int* __restrict__ cellid,
    int* __restrict__ cursor, float4* __restrict__ spts,
    int* __restrict__ sidx, int* __restrict__ cells_s) {
  const int g = blockIdx.x * 256 + threadIdx.x;
  const int b = g / K;
  const int c = cellid[g];
  const int pos = atomicAdd(&cursor[b * OST + c], 1);
  spts[b * K + pos] = pack[g];
  sidx[b * K + pos] = g - b * K;
  cells_s[b * K + pos] = c;
}

// Wave-per-query exact shell search.
__global__ __launch_bounds__(256) void search_wave_kernel(
    const float4* __restrict__ spts, const int* __restrict__ sidx,
    const int* __restrict__ cells_s, const int* __restrict__ offs,
    float* __restrict__ value) {
  const int wid  = blockIdx.x * 4 + (threadIdx.x >> 6);  // global wave = query
  const int lane = threadIdx.x & 63;
  const int b = wid / K;
  const int sbase = b * K;
  const int obase = b * OST;

  const float4 q = spts[wid];
  const float qx = q.x, qy = q.y, qz = q.z, qn = q.w;
  const int c = cells_s[wid];
  const int cx = c % G, cy = (c / G) % G, cz = c / (G * G);

  float e0 = BIG, e1 = BIG, e2 = BIG;

#define PAIR(I)                                                \
  do {                                                         \
    const float4 sp = spts[sbase + (I)];                       \
    const float dot_ = (qx * sp.x + qy * sp.y) + qz * sp.z;    \
    const float d_ = (qn - 2.0f * dot_) + sp.w;                \
    MINSERT(d_, e0, e1, e2);                                   \
  } while (0)

  for (int s = 0; s < G; ++s) {
    const int zlo = max(cz - s, 0), zhi = min(cz + s, G - 1);
    for (int z = zlo; z <= zhi; ++z) {
      const bool zface = (z == cz - s) || (z == cz + s);
      const int ylo = max(cy - s, 0), yhi = min(cy + s, G - 1);
      for (int y = ylo; y <= yhi; ++y) {
        const int rowb = obase + (z * G + y) * G;
        if (zface || y == cy - s || y == cy + s) {
          const int xlo = max(cx - s, 0), xhi = min(cx + s, G - 1);
          const int st = offs[rowb + xlo];
          const int en = offs[rowb + xhi + 1];
          for (int i = st + lane; i < en; i += 64) PAIR(i);
        } else {
          const int xa = cx - s;
          if (xa >= 0) {
            const int st = offs[rowb + xa], en = offs[rowb + xa + 1];
            for (int i = st + lane; i < en; i += 64) PAIR(i);
          }
          const int xb = cx + s;
          if (xb < G) {
            const int st = offs[rowb + xb], en = offs[rowb + xb + 1];
            for (int i = st + lane; i < en; i += 64) PAIR(i);
          }
        }
      }
    }
    // Wave-global 3rd-smallest so far (tree merge of COPIES; lane0 exact).
    float t0 = e0, t1 = e1, t2 = e2;
#pragma unroll
    for (int off = 32; off; off >>= 1) {
      const float f0 = __shfl_down(t0, off, 64);
      const float f1 = __shfl_down(t1, off, 64);
      const float f2 = __shfl_down(t2, off, 64);
      MINSERT(f0, t0, t1, t2);
      MINSERT(f1, t0, t1, t2);
      MINSERT(f2, t0, t1, t2);
    }
    const float g2 = __shfl(t2, 0, 64);
    // Min distance to any unvisited cell (faces of visited box; grid edge ->
    // BIG, which also makes clamped-outlier handling exact). Margin 1e-5
    // dominates all fl rounding (faces are dyadic-exact here).
    const float rxlo = (cx - s >= 1)      ? (qx - (LOB + (float)(cx - s) * CW))      : BIG;
    const float rxhi = (cx + s + 1 <= G - 1) ? ((LOB + (float)(cx + s + 1) * CW) - qx) : BIG;
    const float rylo = (cy - s >= 1)      ? (qy - (LOB + (float)(cy - s) * CW))      : BIG;
    const float ryhi = (cy + s + 1 <= G - 1) ? ((LOB + (float)(cy + s + 1) * CW) - qy) : BIG;
    const float rzlo = (cz - s >= 1)      ? (qz - (LOB + (float)(cz - s) * CW))      : BIG;
    const float rzhi = (cz + s + 1 <= G - 1) ? ((LOB + (float)(cz + s + 1) * CW) - qz) : BIG;
    const float rmin = fminf(fminf(fminf(rxlo, rxhi), fminf(rylo, ryhi)),
                             fminf(rzlo, rzhi));
    const float rs = fmaxf(rmin - 1e-5f, 0.0f);
    if (g2 < 1e37f && g2 <= rs * rs) break;
  }
#undef PAIR

  // Final exact merge (each lane's triple enters lane0's path exactly once).
#pragma unroll
  for (int off = 32; off; off >>= 1) {
    const float f0 = __shfl_down(e0, off, 64);
    const float f1 = __shfl_down(e1, off, 64);
    const float f2 = __shfl_down(e2, off, 64);
    MINSERT(f0, e0, e1, e2);
    MINSERT(f1, e0, e1, e2);
    MINSERT(f2, e0, e1, e2);
  }
  if (lane == 0) {
    // drop self (e0 == +0.0 exactly), mean of 2 kNN
    value[sbase + sidx[wid]] = 0.5f * (e1 + e2);
  }
}

// Per-256-chunk double sums of value (fixed order -> deterministic).
__global__ __launch_bounds__(256) void bsum_kernel(
    const float* __restrict__ value, double* __restrict__ bsum) {
  const int blk = blockIdx.x;  // b*32 + sub  (K = 32*256)
  const int tid = threadIdx.x;
  const float v = value[blk * 256 + tid];

  double s = (double)v, s2 = (double)v * (double)v;
  for (int off = 32; off > 0; off >>= 1) {
    s  += __shfl_down(s, off, 64);
    s2 += __shfl_down(s2, off, 64);
  }
  __shared__ double rs[4], rs2[4];
  const int wave = tid >> 6;
  if ((tid & 63) == 0) { rs[wave] = s; rs2[wave] = s2; }
  __syncthreads();
  if (tid == 0) {
    double S = 0.0, S2 = 0.0;
    for (int wv = 0; wv < 4; ++wv) { S += rs[wv]; S2 += rs2[wv]; }
    bsum[blk * 2 + 0] = S;
    bsum[blk * 2 + 1] = S2;
  }
}

// Threshold (recomputed per block, fixed order -> deterministic) + mask.
__global__ __launch_bounds__(256) void sor_mask_kernel(
    const float* __restrict__ x, const float* __restrict__ value,
    const double* __restrict__ bsum, float* __restrict__ out) {
  const int g = blockIdx.x * 256 + threadIdx.x;  // b*K + k
  const int b = g / K;

  __shared__ float sthr;
  if (threadIdx.x == 0) {
    double S = 0.0, S2 = 0.0;
    for (int wv = 0; wv < 32; ++wv) {
      S  += bsum[(b * 32 + wv) * 2 + 0];
      S2 += bsum[(b * 32 + wv) * 2 + 1];
    }
    const double mean = S / (double)K;
    const double var  = (S2 - S * S / (double)K) / (double)(K - 1);
    sthr = (float)(mean + 1.1 * sqrt(var));
  }
  __syncthreads();

  const float m = (value[g] <= sthr) ? 1.0f : 0.0f;
  out[(size_t)BK * 3 + g] = m;
  const size_t base = (size_t)g * 3;
  out[base + 0] = x[base + 0] * m;
  out[base + 1] = x[base + 1] * m;
  out[base + 2] = x[base + 2] * m;
}

extern "C" void kernel_launch(void* const* d_in, const int* in_sizes, int n_in,
                              void* d_out, int out_size, void* d_ws, size_t ws_size,
                              hipStream_t stream) {
  const float* x = (const float*)d_in[0];
  float* out = (float*)d_out;
  char* ws = (char*)d_ws;

  size_t off = 0;
  float4* pack = (float4*)(ws + off); off += (size_t)BK * sizeof(float4);
  float4* spts = (float4*)(ws + off); off += (size_t)BK * sizeof(float4);
  int* cellid  = (int*)(ws + off);    off += (size_t)BK * sizeof(int);
  int* sidx    = (int*)(ws + off);    off += (size_t)BK * sizeof(int);
  int* cells_s = (int*)(ws + off);    off += (size_t)BK * sizeof(int);
  int* counts  = (int*)(ws + off);    off += (size_t)B * NC * sizeof(int);
  int* offs    = (int*)(ws + off);    off += (size_t)B * OST * sizeof(int);
  int* cursor  = (int*)(ws + off);    off += (size_t)B * OST * sizeof(int);
  float* value = (float*)(ws + off);  off += (size_t)BK * sizeof(float);
  off = (off + 15) & ~(size_t)15;
  double* bsum = (double*)(ws + off);

  hipMemsetAsync(counts, 0, (size_t)B * NC * sizeof(int), stream);
  pack_cell_kernel<<<BK / 256, 256, 0, stream>>>(x, pack, cellid, counts);
  scan_kernel<<<B, 1024, 0, stream>>>(counts, offs, cursor);
  scatter_kernel<<<BK / 256, 256, 0, stream>>>(pack, cellid, cursor,
                                               spts, sidx, cells_s);
  search_wave_kernel<<<BK / 4, 256, 0, stream>>>(spts, sidx, cells_s, offs,
                                                 value);
  bsum_kernel<<<BK / 256, 256, 0, stream>>>(value, bsum);
  sor_mask_kernel<<<BK / 256, 256, 0, stream>>>(x, value, bsum, out);
}

// Round 10
// 185.198 us; speedup vs baseline: 2.3247x; 1.8356x over previous
//
#include <hip/hip_runtime.h>
#include <math.h>

// SOR defense: B=4, K=8192, 3D points. kNN k=2 (3 smallest incl. self).
// Outputs: masked_pc [4,8192,3] then mask [4,8192] (floats).
//
// Exact z-band kNN: bucket-sort by z (8192 exact dyadic buckets); a wave owns
// 64 z-consecutive queries and scans a contiguous wave-uniform band of sorted
// points via SGPR broadcast (s_load_dwordx16, double-buffered), expanding
// 64 points/side until every lane's 3rd-smallest beats the bucket-edge gap
// bound (conservative margin). Distance expression textually identical to the
// validated all-pairs rounds -> exact top-3 multiset -> identical outputs,
// independent of scatter order (bucket-of-position is deterministic).

constexpr int B = 4;
constexpr int K = 8192;
constexpr int BK = B * K;
constexpr int NC = 8192;            // z-buckets per batch
constexpr int OST = NC + 4;         // padded per-batch offs stride
constexpr float LOBZ = -4.5f;
constexpr float HIBZ = 4.5f;
constexpr float WZ = (HIBZ - LOBZ) / (float)NC;  // 9/8192, exact in f32
#define MARGIN 1e-3f

#define BIG 3.0e38f

using f32x16 = __attribute__((ext_vector_type(16))) float;

// Exact top-3 insert via med3 (pure selection, exact order statistics).
#define MINSERT(d, e0, e1, e2)                                  \
  do {                                                          \
    const float n0_ = fminf((e0), (d));                         \
    const float n1_ = __builtin_amdgcn_fmed3f((d), (e0), (e1)); \
    const float n2_ = __builtin_amdgcn_fmed3f((d), (e1), (e2)); \
    (e0) = n0_; (e1) = n1_; (e2) = n2_;                         \
  } while (0)

// Pack (x,y,z,||p||^2), z-bucket id, histogram. Norm expression identical to
// reference xx -> bit-identical downstream.
__global__ __launch_bounds__(256) void pack_cell_kernel(
    const float* __restrict__ x, float4* __restrict__ pack,
    int* __restrict__ cellid, int* __restrict__ counts) {
  const int g = blockIdx.x * 256 + threadIdx.x;  // over B*K
  const int b = g / K;
  const float px = x[(size_t)g * 3 + 0];
  const float py = x[(size_t)g * 3 + 1];
  const float pz = x[(size_t)g * 3 + 2];
  pack[g] = make_float4(px, py, pz, (px * px + py * py) + pz * pz);

  const float SC = (float)NC / (HIBZ - LOBZ);
  int c = (int)((pz - LOBZ) * SC);
  c = min(max(c, 0), NC - 1);
  cellid[g] = c;
  atomicAdd(&counts[b * NC + c], 1);
}

// Per-batch exclusive scan over NC buckets (1024 threads x 8, int4-vectorized).
__global__ __launch_bounds__(1024) void scan_kernel(
    const int* __restrict__ counts, int* __restrict__ offs,
    int* __restrict__ cursor) {
  const int b = blockIdx.x;
  const int t = threadIdx.x;
  const int base = b * NC + t * 8;

  int4 c[2];
  const int4* cp = (const int4*)(counts + base);
  int sum = 0;
#pragma unroll
  for (int i = 0; i < 2; ++i) {
    c[i] = cp[i];
    sum += c[i].x + c[i].y + c[i].z + c[i].w;
  }

  __shared__ int ss[1024];
  ss[t] = sum;
  __syncthreads();
  for (int off = 1; off < 1024; off <<= 1) {  // Hillis-Steele inclusive
    const int v = (t >= off) ? ss[t - off] : 0;
    __syncthreads();
    ss[t] += v;
    __syncthreads();
  }

  int run = ss[t] - sum;  // exclusive start
  const int obase = b * OST;
  int4* op = (int4*)(offs + obase + t * 8);
  int4* up = (int4*)(cursor + obase + t * 8);
#pragma unroll
  for (int i = 0; i < 2; ++i) {
    int4 o;
    o.x = run; run += c[i].x;
    o.y = run; run += c[i].y;
    o.z = run; run += c[i].z;
    o.w = run; run += c[i].w;
    op[i] = o;
    up[i] = o;
  }
  if (t == 1023) offs[obase + NC] = run;  // == K
}

// Scatter into z-bucket-sorted order (in-bucket order nondeterministic; the
// band stop-guarantee makes final top-3 permutation-independent).
__global__ __launch_bounds__(256) void scatter_kernel(
    const float4* __restrict__ pack, const int* __restrict__ cellid,
    int* __restrict__ cursor, float4* __restrict__ spts,
    int* __restrict__ sidx, int* __restrict__ cells_s) {
  const int g = blockIdx.x * 256 + threadIdx.x;
  const int b = g / K;
  const int c = cellid[g];
  const int pos = atomicAdd(&cursor[b * OST + c], 1);
  spts[b * K + pos] = pack[g];
  sidx[b * K + pos] = g - b * K;
  cells_s[b * K + pos] = c;
}

// One (point, query) update; distance text identical to validated rounds.
#define PAIRQ(X, Y, Z, W)                                   \
  do {                                                      \
    const float dot_ = (qx * (X) + qy * (Y)) + qz * (Z);    \
    const float d_ = (qn - 2.0f * dot_) + (W);              \
    MINSERT(d_, e0, e1, e2);                                \
  } while (0)

#define COMP16(Cv)                                           \
  do {                                                       \
    PAIRQ((Cv)[0], (Cv)[1], (Cv)[2], (Cv)[3]);               \
    PAIRQ((Cv)[4], (Cv)[5], (Cv)[6], (Cv)[7]);               \
    PAIRQ((Cv)[8], (Cv)[9], (Cv)[10], (Cv)[11]);             \
    PAIRQ((Cv)[12], (Cv)[13], (Cv)[14], (Cv)[15]);           \
  } while (0)

#define SL16(DST, PTR)                                                  \
  asm volatile("s_load_dwordx16 %0, %1, 0x0" : "=s"(DST) : "s"(PTR))
#define SWAIT2(R0, R1)                                                  \
  asm volatile("s_waitcnt lgkmcnt(0)" : "+s"(R0), "+s"(R1))

// Scan 64 sorted points [LO, LO+64) via double-buffered SGPR broadcast.
#define SCAN64(LO)                                                      \
  do {                                                                  \
    const float4* p_ = spts + sbase + (LO);                             \
    f32x16 A0_, A1_, B0_, B1_;                                          \
    SL16(A0_, p_); SL16(A1_, p_ + 4);                                   \
    _Pragma("unroll")                                                   \
    for (int t_ = 0; t_ < 4; ++t_) {                                    \
      SWAIT2(A0_, A1_);                                                 \
      SL16(B0_, p_ + 16 * t_ + 8); SL16(B1_, p_ + 16 * t_ + 12);        \
      __builtin_amdgcn_sched_barrier(0);                                \
      COMP16(A0_); COMP16(A1_);                                         \
      SWAIT2(B0_, B1_);                                                 \
      if (t_ < 3) { SL16(A0_, p_ + 16 * t_ + 16); SL16(A1_, p_ + 16 * t_ + 20); } \
      __builtin_amdgcn_sched_barrier(0);                                \
      COMP16(B0_); COMP16(B1_);                                         \
    }                                                                   \
  } while (0)

// Wave = 64 z-consecutive sorted queries (lane = query); shared band scan.
__global__ __launch_bounds__(64) void search_band_kernel(
    const float4* __restrict__ spts, const int* __restrict__ sidx,
    const int* __restrict__ cells_s, float* __restrict__ value) {
  const int wid = blockIdx.x;           // 0 .. B*K/64-1
  const int lane = threadIdx.x;
  const int b = wid >> 7;               // K/64 = 128 waves per batch
  const int q0 = (wid & 127) << 6;      // batch-local sorted position
  const int sbase = b * K;

  const float4 qp = spts[sbase + q0 + lane];
  const float qx = qp.x, qy = qp.y, qz = qp.z, qn = qp.w;

  float e0 = BIG, e1 = BIG, e2 = BIG;

  SCAN64(q0);                           // own block (includes self)
  int L = q0, R = q0 + 64;

  while (true) {
    // Gap to nearest unscanned point, via exact bucket edges.
    // Left: unscanned j<L have z <= edge(bucket(L-1)+1); right: z >= edge(bucket(R)).
    float gl = BIG, gr = BIG;
    if (L > 0)
      gl = fmaxf(qz - (LOBZ + (float)(cells_s[sbase + L - 1] + 1) * WZ), 0.0f);
    if (R < K)
      gr = fmaxf((LOBZ + (float)cells_s[sbase + R] * WZ) - qz, 0.0f);
    const bool allL = __all(e2 <= gl * gl - MARGIN);
    const bool allR = __all(e2 <= gr * gr - MARGIN);
    if (allL && allR) break;
    if (!allL) { L -= 64; SCAN64(L); }
    if (!allR) { SCAN64(R); R += 64; }
  }

  // drop self (e0), mean of 2 kNN; scatter back to original k.
  value[sbase + sidx[sbase + q0 + lane]] = 0.5f * (e1 + e2);
}

// Per-256-chunk double sums of value (fixed order -> deterministic).
__global__ __launch_bounds__(256) void bsum_kernel(
    const float* __restrict__ value, double* __restrict__ bsum) {
  const int blk = blockIdx.x;  // b*32 + sub  (K = 32*256)
  const int tid = threadIdx.x;
  const float v = value[blk * 256 + tid];

  double s = (double)v, s2 = (double)v * (double)v;
  for (int off = 32; off > 0; off >>= 1) {
    s  += __shfl_down(s, off, 64);
    s2 += __shfl_down(s2, off, 64);
  }
  __shared__ double rs[4], rs2[4];
  const int wave = tid >> 6;
  if ((tid & 63) == 0) { rs[wave] = s; rs2[wave] = s2; }
  __syncthreads();
  if (tid == 0) {
    double S = 0.0, S2 = 0.0;
    for (int wv = 0; wv < 4; ++wv) { S += rs[wv]; S2 += rs2[wv]; }
    bsum[blk * 2 + 0] = S;
    bsum[blk * 2 + 1] = S2;
  }
}

// Threshold (recomputed per block, fixed order -> deterministic) + mask.
__global__ __launch_bounds__(256) void sor_mask_kernel(
    const float* __restrict__ x, const float* __restrict__ value,
    const double* __restrict__ bsum, float* __restrict__ out) {
  const int g = blockIdx.x * 256 + threadIdx.x;  // b*K + k
  const int b = g / K;

  __shared__ float sthr;
  if (threadIdx.x == 0) {
    double S = 0.0, S2 = 0.0;
    for (int wv = 0; wv < 32; ++wv) {
      S  += bsum[(b * 32 + wv) * 2 + 0];
      S2 += bsum[(b * 32 + wv) * 2 + 1];
    }
    const double mean = S / (double)K;
    const double var  = (S2 - S * S / (double)K) / (double)(K - 1);
    sthr = (float)(mean + 1.1 * sqrt(var));
  }
  __syncthreads();

  const float m = (value[g] <= sthr) ? 1.0f : 0.0f;
  out[(size_t)BK * 3 + g] = m;
  const size_t base = (size_t)g * 3;
  out[base + 0] = x[base + 0] * m;
  out[base + 1] = x[base + 1] * m;
  out[base + 2] = x[base + 2] * m;
}

extern "C" void kernel_launch(void* const* d_in, const int* in_sizes, int n_in,
                              void* d_out, int out_size, void* d_ws, size_t ws_size,
                              hipStream_t stream) {
  const float* x = (const float*)d_in[0];
  float* out = (float*)d_out;
  char* ws = (char*)d_ws;

  size_t off = 0;
  float4* pack = (float4*)(ws + off); off += (size_t)BK * sizeof(float4);
  float4* spts = (float4*)(ws + off); off += (size_t)BK * sizeof(float4);
  int* cellid  = (int*)(ws + off);    off += (size_t)BK * sizeof(int);
  int* sidx    = (int*)(ws + off);    off += (size_t)BK * sizeof(int);
  int* cells_s = (int*)(ws + off);    off += (size_t)BK * sizeof(int);
  int* counts  = (int*)(ws + off);    off += (size_t)B * NC * sizeof(int);
  int* offs    = (int*)(ws + off);    off += (size_t)B * OST * sizeof(int);
  int* cursor  = (int*)(ws + off);    off += (size_t)B * OST * sizeof(int);
  float* value = (float*)(ws + off);  off += (size_t)BK * sizeof(float);
  off = (off + 15) & ~(size_t)15;
  double* bsum = (double*)(ws + off);

  hipMemsetAsync(counts, 0, (size_t)B * NC * sizeof(int), stream);
  pack_cell_kernel<<<BK / 256, 256, 0, stream>>>(x, pack, cellid, counts);
  scan_kernel<<<B, 1024, 0, stream>>>(counts, offs, cursor);
  scatter_kernel<<<BK / 256, 256, 0, stream>>>(pack, cellid, cursor,
                                               spts, sidx, cells_s);
  search_band_kernel<<<BK / 64, 64, 0, stream>>>(spts, sidx, cells_s, value);
  bsum_kernel<<<BK / 256, 256, 0, stream>>>(value, bsum);
  sor_mask_kernel<<<BK / 256, 256, 0, stream>>>(x, value, bsum, out);
}

// Round 14
// 84.330 us; speedup vs baseline: 5.1052x; 2.1961x over previous
//
#include <hip/hip_runtime.h>
#include <math.h>

// SOR defense: B=4, K=8192, 3D points. kNN k=2 (3 smallest incl. self).
// Outputs: masked_pc [4,8192,3] then mask [4,8192] (floats).
//
// Exact z-band kNN, two-phase:
//  phase 1: each query's top-3 over its own 64 sorted z-neighbors -> e2_ub
//           (upper bound on true 3rd-smallest, subset property).
//  phase 2: band [L,R) from r = sqrt(e2_ub)+2e-3 via exact bucket edges is a
//           superset of the true top-3; PARTITIONED across 8 waves (no
//           duplicates), each scanning via ping-pong s_load_dwordx16 SGPR
//           broadcast (each buffer waited BEFORE its compute, no copies);
//           LDS merge of partial triples.
// Wave-uniform values pinned to SGPRs with readfirstlane (exact: lanes
// identical after butterfly reduce / per-wave constants).
// Distance expression textually identical to validated rounds -> bit-exact.

constexpr int B = 4;
constexpr int K = 8192;
constexpr int BK = B * K;
constexpr int NC = 8192;            // z-buckets per batch
constexpr int OST = NC + 4;         // padded per-batch offs stride
constexpr float LOBZ = -4.5f;
constexpr float HIBZ = 4.5f;

#define BIG 3.0e38f

using f32x16 = __attribute__((ext_vector_type(16))) float;

// Exact top-3 insert via med3 (pure selection, exact order statistics).
#define MINSERT(d, e0, e1, e2)                                  \
  do {                                                          \
    const float n0_ = fminf((e0), (d));                         \
    const float n1_ = __builtin_amdgcn_fmed3f((d), (e0), (e1)); \
    const float n2_ = __builtin_amdgcn_fmed3f((d), (e1), (e2)); \
    (e0) = n0_; (e1) = n1_; (e2) = n2_;                         \
  } while (0)

// Pack (x,y,z,||p||^2), z-bucket id, histogram. Norm expression identical to
// reference xx -> bit-identical downstream.
__global__ __launch_bounds__(256) void pack_cell_kernel(
    const float* __restrict__ x, float4* __restrict__ pack,
    int* __restrict__ cellid, int* __restrict__ counts) {
  const int g = blockIdx.x * 256 + threadIdx.x;  // over B*K
  const int b = g / K;
  const float px = x[(size_t)g * 3 + 0];
  const float py = x[(size_t)g * 3 + 1];
  const float pz = x[(size_t)g * 3 + 2];
  pack[g] = make_float4(px, py, pz, (px * px + py * py) + pz * pz);

  const float SC = (float)NC / (HIBZ - LOBZ);
  int c = (int)((pz - LOBZ) * SC);
  c = min(max(c, 0), NC - 1);
  cellid[g] = c;
  atomicAdd(&counts[b * NC + c], 1);
}

// Per-batch exclusive scan over NC buckets (1024 threads x 8, int4-vectorized).
__global__ __launch_bounds__(1024) void scan_kernel(
    const int* __restrict__ counts, int* __restrict__ offs,
    int* __restrict__ cursor) {
  const int b = blockIdx.x;
  const int t = threadIdx.x;
  const int base = b * NC + t * 8;

  int4 c[2];
  const int4* cp = (const int4*)(counts + base);
  int sum = 0;
#pragma unroll
  for (int i = 0; i < 2; ++i) {
    c[i] = cp[i];
    sum += c[i].x + c[i].y + c[i].z + c[i].w;
  }

  __shared__ int ss[1024];
  ss[t] = sum;
  __syncthreads();
  for (int off = 1; off < 1024; off <<= 1) {  // Hillis-Steele inclusive
    const int v = (t >= off) ? ss[t - off] : 0;
    __syncthreads();
    ss[t] += v;
    __syncthreads();
  }

  int run = ss[t] - sum;  // exclusive start
  const int obase = b * OST;
  int4* op = (int4*)(offs + obase + t * 8);
  int4* up = (int4*)(cursor + obase + t * 8);
#pragma unroll
  for (int i = 0; i < 2; ++i) {
    int4 o;
    o.x = run; run += c[i].x;
    o.y = run; run += c[i].y;
    o.z = run; run += c[i].z;
    o.w = run; run += c[i].w;
    op[i] = o;
    up[i] = o;
  }
  if (t == 1023) offs[obase + NC] = run;  // == K
}

// Scatter into z-bucket-sorted order.
__global__ __launch_bounds__(256) void scatter_kernel(
    const float4* __restrict__ pack, const int* __restrict__ cellid,
    int* __restrict__ cursor, float4* __restrict__ spts,
    int* __restrict__ sidx) {
  const int g = blockIdx.x * 256 + threadIdx.x;
  const int b = g / K;
  const int c = cellid[g];
  const int pos = atomicAdd(&cursor[b * OST + c], 1);
  spts[b * K + pos] = pack[g];
  sidx[b * K + pos] = g - b * K;
}

// One (point, query) update; distance text identical to validated rounds.
#define PAIRQ(X, Y, Z, W)                                   \
  do {                                                      \
    const float dot_ = (qx * (X) + qy * (Y)) + qz * (Z);    \
    const float d_ = (qn - 2.0f * dot_) + (W);              \
    MINSERT(d_, e0, e1, e2);                                \
  } while (0)

#define COMP16(Cv)                                           \
  do {                                                       \
    PAIRQ((Cv)[0], (Cv)[1], (Cv)[2], (Cv)[3]);               \
    PAIRQ((Cv)[4], (Cv)[5], (Cv)[6], (Cv)[7]);               \
    PAIRQ((Cv)[8], (Cv)[9], (Cv)[10], (Cv)[11]);             \
    PAIRQ((Cv)[12], (Cv)[13], (Cv)[14], (Cv)[15]);           \
  } while (0)

#define SL16(DST, PTR)                                                  \
  asm volatile("s_load_dwordx16 %0, %1, 0x0" : "=s"(DST) : "s"(PTR))
#define SWAIT2(R0, R1)                                                  \
  asm volatile("s_waitcnt lgkmcnt(0)" : "+s"(R0), "+s"(R1))

// Scan 64 sorted points [LO, LO+64) via double-buffered SGPR broadcast.
// (Validated structure: every buffer is waited between its loads and its
// compute; no un-waited register copies.)
#define SCAN64(LO)                                                      \
  do {                                                                  \
    const float4* p_ = spts + sbase + (LO);                             \
    f32x16 A0_, A1_, B0_, B1_;                                          \
    SL16(A0_, p_); SL16(A1_, p_ + 4);                                   \
    _Pragma("unroll")                                                   \
    for (int t_ = 0; t_ < 4; ++t_) {                                    \
      SWAIT2(A0_, A1_);                                                 \
      SL16(B0_, p_ + 16 * t_ + 8); SL16(B1_, p_ + 16 * t_ + 12);        \
      __builtin_amdgcn_sched_barrier(0);                                \
      COMP16(A0_); COMP16(A1_);                                         \
      SWAIT2(B0_, B1_);                                                 \
      if (t_ < 3) { SL16(A0_, p_ + 16 * t_ + 16); SL16(A1_, p_ + 16 * t_ + 20); } \
      __builtin_amdgcn_sched_barrier(0);                                \
      COMP16(B0_); COMP16(B1_);                                         \
    }                                                                   \
  } while (0)

// Block = 64 z-consecutive sorted queries (lane = query), 8 waves split the
// band; straight-line, no ballots, no adaptive loop.
__global__ __launch_bounds__(512) void search_band_kernel(
    const float4* __restrict__ spts, const int* __restrict__ sidx,
    const int* __restrict__ offs, float* __restrict__ value) {
  const int blk  = blockIdx.x;            // 0 .. B*K/64-1
  const int b    = blk >> 7;              // 128 blocks per batch
  const int q0   = (blk & 127) << 6;      // batch-local sorted position
  const int wv   = threadIdx.x >> 6;      // 0..7
  const int lane = threadIdx.x & 63;
  const int sbase = b * K;
  const int obase = b * OST;

  const float4 qp = spts[sbase + q0 + lane];
  const float qx = qp.x, qy = qp.y, qz = qp.z, qn = qp.w;

  // ---- Phase 1: bound over own 64-block (redundant per wave, cheap) ----
  float e0 = BIG, e1 = BIG, e2 = BIG;
  SCAN64(q0);

  // r upper-bounds the true 3rd-NN distance; +2e-3 dominates all fl rounding
  // of edges/distances (~1.8 buckets of margin at SC~910/unit).
  float r = sqrtf(fmaxf(e2, 0.0f)) + 2e-3f;
  float zmn = qz, zmx = qz;
#pragma unroll
  for (int off = 32; off; off >>= 1) {
    r   = fmaxf(r,   __shfl_xor(r,   off, 64));
    zmn = fminf(zmn, __shfl_xor(zmn, off, 64));
    zmx = fmaxf(zmx, __shfl_xor(zmx, off, 64));
  }

  const float SC = (float)NC / (HIBZ - LOBZ);
  int cL = (int)((zmn - r - LOBZ) * SC); cL = min(max(cL, 0), NC - 1);
  int cR = (int)((zmx + r - LOBZ) * SC); cR = min(max(cR, 0), NC - 1);
  // Pin wave-uniform values to SGPRs (all lanes identical after reduce).
  cL = __builtin_amdgcn_readfirstlane(cL);
  cR = __builtin_amdgcn_readfirstlane(cR);
  const int L = __builtin_amdgcn_readfirstlane(offs[obase + cL]);
  const int R = __builtin_amdgcn_readfirstlane(offs[obase + cR + 1]);

  // ---- Phase 2: partitioned band scan (fresh state; band covers q0 block) --
  e0 = BIG; e1 = BIG; e2 = BIG;

  const int len   = R - L;
  const int nfull = len >> 3;        // full 8-point chunks
  const int cbase = nfull >> 3, crem = nfull & 7;
  // wv is constant within a wave -> readfirstlane exact, forces SGPR.
  const int c0 = __builtin_amdgcn_readfirstlane(wv * cbase + min(wv, crem));
  const int c1 = __builtin_amdgcn_readfirstlane(
      wv * cbase + min(wv, crem) + cbase + (wv < crem ? 1 : 0));

  // Ping-pong over 8-point chunks; each buffer waited before its compute,
  // NO register copies (the R13 bug was an un-waited B->A copy).
  {
    int c = c0;
    const float4* p = spts + sbase + L + 8 * c0;
    f32x16 A0, A1, B0, B1;
    if (c < c1) { SL16(A0, p); SL16(A1, p + 4); }
    while (c < c1) {
      SWAIT2(A0, A1);
      const bool haveB = (c + 1 < c1);
      if (haveB) { SL16(B0, p + 8); SL16(B1, p + 12); }
      __builtin_amdgcn_sched_barrier(0);
      COMP16(A0); COMP16(A1);
      ++c; p += 8;
      if (!haveB) break;
      SWAIT2(B0, B1);
      if (c + 1 < c1) { SL16(A0, p + 8); SL16(A1, p + 12); }
      __builtin_amdgcn_sched_barrier(0);
      COMP16(B0); COMP16(B1);
      ++c; p += 8;
    }
  }
  if (wv == 7) {  // guarded tail (< 8 points), wave-uniform count
    for (int i = L + (nfull << 3); i < R; ++i) {
      const float4 sp = spts[sbase + i];
      PAIRQ(sp.x, sp.y, sp.z, sp.w);
    }
  }

  // ---- Merge 8 partial triples per query via LDS ----
  __shared__ float sm[8][64][3];
  sm[wv][lane][0] = e0;
  sm[wv][lane][1] = e1;
  sm[wv][lane][2] = e2;
  __syncthreads();

  if (wv == 0) {
    float d0 = BIG, d1 = BIG, d2 = BIG;
#pragma unroll
    for (int w = 0; w < 8; ++w) {
      const float a0 = sm[w][lane][0];
      const float a1 = sm[w][lane][1];
      const float a2 = sm[w][lane][2];
      MINSERT(a0, d0, d1, d2);
      MINSERT(a1, d0, d1, d2);
      MINSERT(a2, d0, d1, d2);
    }
    // drop self (d0 = smallest), mean of 2 kNN
    value[sbase + sidx[sbase + q0 + lane]] = 0.5f * (d1 + d2);
  }
}

// Per-256-chunk double sums of value (fixed order -> deterministic).
__global__ __launch_bounds__(256) void bsum_kernel(
    const float* __restrict__ value, double* __restrict__ bsum) {
  const int blk = blockIdx.x;  // b*32 + sub  (K = 32*256)
  const int tid = threadIdx.x;
  const float v = value[blk * 256 + tid];

  double s = (double)v, s2 = (double)v * (double)v;
  for (int off = 32; off > 0; off >>= 1) {
    s  += __shfl_down(s, off, 64);
    s2 += __shfl_down(s2, off, 64);
  }
  __shared__ double rs[4], rs2[4];
  const int wave = tid >> 6;
  if ((tid & 63) == 0) { rs[wave] = s; rs2[wave] = s2; }
  __syncthreads();
  if (tid == 0) {
    double S = 0.0, S2 = 0.0;
    for (int wv = 0; wv < 4; ++wv) { S += rs[wv]; S2 += rs2[wv]; }
    bsum[blk * 2 + 0] = S;
    bsum[blk * 2 + 1] = S2;
  }
}

// Threshold (recomputed per block, fixed order -> deterministic) + mask.
__global__ __launch_bounds__(256) void sor_mask_kernel(
    const float* __restrict__ x, const float* __restrict__ value,
    const double* __restrict__ bsum, float* __restrict__ out) {
  const int g = blockIdx.x * 256 + threadIdx.x;  // b*K + k
  const int b = g / K;

  __shared__ float sthr;
  if (threadIdx.x == 0) {
    double S = 0.0, S2 = 0.0;
    for (int wv = 0; wv < 32; ++wv) {
      S  += bsum[(b * 32 + wv) * 2 + 0];
      S2 += bsum[(b * 32 + wv) * 2 + 1];
    }
    const double mean = S / (double)K;
    const double var  = (S2 - S * S / (double)K) / (double)(K - 1);
    sthr = (float)(mean + 1.1 * sqrt(var));
  }
  __syncthreads();

  const float m = (value[g] <= sthr) ? 1.0f : 0.0f;
  out[(size_t)BK * 3 + g] = m;
  const size_t base = (size_t)g * 3;
  out[base + 0] = x[base + 0] * m;
  out[base + 1] = x[base + 1] * m;
  out[base + 2] = x[base + 2] * m;
}

extern "C" void kernel_launch(void* const* d_in, const int* in_sizes, int n_in,
                              void* d_out, int out_size, void* d_ws, size_t ws_size,
                              hipStream_t stream) {
  const float* x = (const float*)d_in[0];
  float* out = (float*)d_out;
  char* ws = (char*)d_ws;

  size_t off = 0;
  float4* pack = (float4*)(ws + off); off += (size_t)BK * sizeof(float4);
  float4* spts = (float4*)(ws + off); off += (size_t)BK * sizeof(float4);
  int* cellid  = (int*)(ws + off);    off += (size_t)BK * sizeof(int);
  int* sidx    = (int*)(ws + off);    off += (size_t)BK * sizeof(int);
  int* counts  = (int*)(ws + off);    off += (size_t)B * NC * sizeof(int);
  int* offs    = (int*)(ws + off);    off += (size_t)B * OST * sizeof(int);
  int* cursor  = (int*)(ws + off);    off += (size_t)B * OST * sizeof(int);
  float* value = (float*)(ws + off);  off += (size_t)BK * sizeof(float);
  off = (off + 15) & ~(size_t)15;
  double* bsum = (double*)(ws + off);

  hipMemsetAsync(counts, 0, (size_t)B * NC * sizeof(int), stream);
  pack_cell_kernel<<<BK / 256, 256, 0, stream>>>(x, pack, cellid, counts);
  scan_kernel<<<B, 1024, 0, stream>>>(counts, offs, cursor);
  scatter_kernel<<<BK / 256, 256, 0, stream>>>(pack, cellid, cursor,
                                               spts, sidx);
  search_band_kernel<<<BK / 64, 512, 0, stream>>>(spts, sidx, offs, value);
  bsum_kernel<<<BK / 256, 256, 0, stream>>>(value, bsum);
  sor_mask_kernel<<<BK / 256, 256, 0, stream>>>(x, value, bsum, out);
}